// Round 2
// baseline (278.773 us; speedup 1.0000x reference)
//
#include <hip/hip_runtime.h>

// Problem: adjacency_full[i, neighbor_indices[i,k]] = adjacency_values[i,k]
// over a zeroed [N,N] fp32 matrix. N=8192, K=64.
//
// v3: two-kernel split.
//   Kernel A (zero_kernel): exact structural clone of __amd_rocclr_fillBufferAligned,
//     which measures 6.5 TB/s on this same output buffer: pure grid-stride float4
//     streamer, no input loads, no barriers, no per-row logic. 2048 blocks x 256 thr,
//     32 float4 per thread.
//   Kernel B (scatter_kernel): 524288 threads, one (idx,val) pair each. Coalesced
//     dword loads of the inputs, one scattered 4 B store. Runs after A completes
//     (same-stream kernel ordering = full memory drain), and its target lines were
//     just written by A so they are L3-resident -> partial-line patch is cheap.
//
// Rationale: v1 (LDS-staged) and v2 (register-streamed + patch) both landed at
// ~97-99 us = 2.7 TB/s effective, 2.4x below the fill kernel's demonstrated rate.
// The invariant between them was the one-block-per-row structure (cold input load
// gating each block's store burst, barrier, lockstep bubbles). This version removes
// every structural difference from the known-6.5TB/s fill for the bulk of the bytes.

constexpr int N_PATCH = 8192;
constexpr int K_NB = 64;

constexpr int ZTHREADS = 256;
constexpr int ZBLOCKS = 2048;                       // 8 blocks/CU on 256 CUs
constexpr size_t TOTAL_F4 = (size_t)N_PATCH * N_PATCH / 4;   // 16 Mi float4
constexpr int ZITERS = (int)(TOTAL_F4 / ((size_t)ZBLOCKS * ZTHREADS));  // 32

__global__ __launch_bounds__(ZTHREADS)
void zero_kernel(float4* __restrict__ out) {
    const size_t base = (size_t)blockIdx.x * ZTHREADS + threadIdx.x;
    constexpr size_t STRIDE = (size_t)ZBLOCKS * ZTHREADS;  // whole-grid window
    const float4 z = make_float4(0.f, 0.f, 0.f, 0.f);
#pragma unroll
    for (int i = 0; i < ZITERS; ++i)
        out[base + (size_t)i * STRIDE] = z;
}

constexpr int STHREADS = 256;
constexpr int SBLOCKS = (N_PATCH * K_NB) / STHREADS;  // 2048

__global__ __launch_bounds__(STHREADS)
void scatter_kernel(const float* __restrict__ vals,
                    const int* __restrict__ idx,
                    float* __restrict__ out) {
    const int g = blockIdx.x * STHREADS + threadIdx.x;  // 0 .. N*K-1
    const int row = g >> 6;                             // g / K_NB
    const int c = idx[g];                               // coalesced
    const float v = vals[g];                            // coalesced
    out[(size_t)row * N_PATCH + c] = v;                 // scattered 4B store
}

extern "C" void kernel_launch(void* const* d_in, const int* in_sizes, int n_in,
                              void* d_out, int out_size, void* d_ws, size_t ws_size,
                              hipStream_t stream) {
    const float* vals = (const float*)d_in[0];   // adjacency_values [N,K] fp32
    const int* idx = (const int*)d_in[1];        // neighbor_indices [N,K] int32
    float* out = (float*)d_out;                  // [N,N] fp32

    zero_kernel<<<ZBLOCKS, ZTHREADS, 0, stream>>>(reinterpret_cast<float4*>(out));
    scatter_kernel<<<SBLOCKS, STHREADS, 0, stream>>>(vals, idx, out);
}

// Round 3
// 272.635 us; speedup vs baseline: 1.0225x; 1.0225x over previous
//
#include <hip/hip_runtime.h>

// Problem: adjacency_full[i, neighbor_indices[i,k]] = adjacency_values[i,k]
// over a zeroed [N,N] fp32 matrix. N=8192, K=64.
//
// v4: zero via hipMemsetAsync (dispatches rocclr's fillBufferAligned — the one
// kernel measured at 6.4 TB/s on this exact machine/context every iteration),
// then patch with a minimal scatter kernel.
//
// Evidence trail: v1 (LDS row-stage), v2 (register-stream + patch), and v3
// (hand-written clone of the fill + scatter) ALL land at 95-108 us of kernel
// time for the same 256 MiB of stores — while fillBufferAligned writes 1 GiB
// at 6.4 TB/s in the same capture window. Structure is exonerated. Theory: the
// measured window runs right after a 1 GiB poison fill, L3 (256 MiB) is full of
// dirty poison lines, and our allocating stores pay dirty-victim writeback on
// every line. rocclr's fill sustains 6.4 TB/s in that same dirty-L3 context, so
// its store/cache policy evidently avoids that penalty — use it directly.

constexpr int N_PATCH = 8192;
constexpr int K_NB = 64;

constexpr int STHREADS = 256;
constexpr int SBLOCKS = (N_PATCH * K_NB) / STHREADS;  // 2048 blocks, 512K threads

__global__ __launch_bounds__(STHREADS)
void scatter_kernel(const float* __restrict__ vals,
                    const int* __restrict__ idx,
                    float* __restrict__ out) {
    const int g = blockIdx.x * STHREADS + threadIdx.x;  // 0 .. N*K-1
    const int row = g >> 6;                             // g / K_NB
    const int c = idx[g];                               // coalesced dword load
    const float v = vals[g];                            // coalesced dword load
    out[(size_t)row * N_PATCH + c] = v;                 // scattered 4B store
}

extern "C" void kernel_launch(void* const* d_in, const int* in_sizes, int n_in,
                              void* d_out, int out_size, void* d_ws, size_t ws_size,
                              hipStream_t stream) {
    const float* vals = (const float*)d_in[0];   // adjacency_values [N,K] fp32
    const int* idx = (const int*)d_in[1];        // neighbor_indices [N,K] int32
    float* out = (float*)d_out;                  // [N,N] fp32

    // Zero the output with the runtime's own fill kernel (stream-ordered,
    // graph-capture-safe memset node; the harness reset() uses the same API).
    hipMemsetAsync(out, 0, (size_t)N_PATCH * N_PATCH * sizeof(float), stream);

    // Patch the K=64 entries per row; same-stream ordering guarantees the
    // memset has fully completed (coherency-point) before these stores issue.
    scatter_kernel<<<SBLOCKS, STHREADS, 0, stream>>>(vals, idx, out);
}